// Round 17
// baseline (1327.263 us; speedup 1.0000x reference)
//
#include <hip/hip_runtime.h>

#define BATCH 32
#define ATOMS 128
#define CCH 3
#define XH 57
#define XW 57
#define OHH 64
#define OWW 64
#define KSEL 2000
#define PIX (XH*XW)            // 3249
#define NPS (ATOMS*PIX)        // 415872
#define NTOT (BATCH*NPS)       // 13307904
#define RPS (CCH*OHH*OWW)      // 12288
#define RTOT (BATCH*RPS)       // 393216
#define CANDCAP 32768
#define NW 24576
#define NWC 32768              // Wcand padded: 128 atoms x 256
#define LCAP 6144
#define ZWORDS (32*2048 + 64)  // g1 + candcnt + done

// ---------------------------------------------------------------------------
// Prep (once): WDd f64 (convD), Wt2f f32 (convDt), Wcand f32 (exact dot),
// Rd = -Y, zero g1/candcnt/done.
// ---------------------------------------------------------------------------
__global__ __launch_bounds__(256) void prep_k(const float* __restrict__ Wg,
    double* __restrict__ WDd, float* __restrict__ Wt2f,
    float* __restrict__ Wcand, const float* __restrict__ Y,
    double* __restrict__ Rd, unsigned* __restrict__ zbuf) {
  int e = blockIdx.x * 256 + threadIdx.x;
  if (e < NW) {
    {
      int kw = e & 7; int t = e >> 3; int c = t % 3; t /= 3; int kh = t & 7; int a = t >> 3;
      WDd[e] = (double)Wg[(a*3 + c)*64 + kh*8 + kw];
    }
    {
      int a = e & 127; int t = e >> 7; int j = t & 7; int i = (t >> 3) & 7; int c = t >> 6;
      Wt2f[e] = Wg[(a*3 + c)*64 + j*8 + i];
    }
  }
  if (e < NWC) {
    int a = e >> 8, r = e & 255;
    float v = 0.0f;
    if (r < 192) {
      int c = r >> 6, ii = (r >> 3) & 7, jj = r & 7;
      v = Wg[(a*3 + c)*64 + jj*8 + ii];
    }
    Wcand[e] = v;
  }
  if (e < RTOT) Rd[e] = -(double)Y[e];
  if (e < ZWORDS) zbuf[e] = 0;
}

// ---------------------------------------------------------------------------
// DENSE R += D(X) (iteration 0 only). Verified r11+ version, unchanged.
// ---------------------------------------------------------------------------
__global__ __launch_bounds__(256) void convD_k(const float* __restrict__ X,
    const double* __restrict__ WDd, double* __restrict__ Rd) {
  __shared__ double Xs[4][11][72];
  int p = blockIdx.x;
  int lg = (p & 7) * 256 + (p >> 3);
  int b = lg >> 6; int rem = lg & 63;
  int band = rem >> 2, quarter = rem & 3;
  int row0 = band * 4;
  int a_base = quarter * 32;
  int tid = threadIdx.x;
  int ox = tid & 63;
  int wv = __builtin_amdgcn_readfirstlane(tid >> 6);
  const float* Xb = X + (size_t)b * NPS;

  double acc[4][3];
#pragma unroll
  for (int ty = 0; ty < 4; ++ty)
#pragma unroll
    for (int c = 0; c < 3; ++c) acc[ty][c] = 0.0;

  for (int ch = 0; ch < 8; ++ch) {
    __syncthreads();
    for (int e = tid; e < 4 * 11 * 72; e += 256) {
      int ai = e / 792; int rem2 = e - ai * 792;
      int r = rem2 / 72; int ss = rem2 - r * 72;
      int gy = row0 - 7 + r;
      int xcol = ss - 7;
      int a = a_base + ch * 4 + ai;
      float v = 0.0f;
      if ((unsigned)xcol < (unsigned)XW && (unsigned)gy < (unsigned)XH)
        v = Xb[a * PIX + gy * XW + xcol];
      Xs[ai][r][ss] = (double)v;
    }
    __syncthreads();
    {
      int a = a_base + ch * 4 + wv;
      const double* Wa = WDd + a * 192;
#pragma unroll
      for (int r = 0; r < 11; ++r) {
        int gy = row0 - 7 + r;
        if ((unsigned)gy >= (unsigned)XH) continue;
        double xd[8];
#pragma unroll
        for (int t = 0; t < 8; ++t) xd[t] = Xs[wv][r][ox + t];
#pragma unroll
        for (int ty = 0; ty < 4; ++ty) {
          int kh = ty + 7 - r;
          if ((unsigned)kh < 8u) {
            const double* Wk = Wa + kh * 24;
#pragma unroll
            for (int kw = 0; kw < 8; ++kw) {
              acc[ty][0] = fma(xd[7 - kw], Wk[kw],      acc[ty][0]);
              acc[ty][1] = fma(xd[7 - kw], Wk[8 + kw],  acc[ty][1]);
              acc[ty][2] = fma(xd[7 - kw], Wk[16 + kw], acc[ty][2]);
            }
          }
        }
      }
    }
  }
#pragma unroll
  for (int ty = 0; ty < 4; ++ty) {
    int oy = row0 + ty;
#pragma unroll
    for (int c = 0; c < 3; ++c)
      atomicAdd(&Rd[((size_t)(b * CCH + c) << 12) + (oy << 6) + ox], acc[ty][c]);
  }
}

// ---------------------------------------------------------------------------
// SPARSE R = D(X) - Y (iterations 1,2). Verified, unchanged.
// ---------------------------------------------------------------------------
__global__ __launch_bounds__(256) void convD_sparse_k(const float* __restrict__ Wg,
    const int* __restrict__ nzidx, const float* __restrict__ nzval,
    const float* __restrict__ Y, float* __restrict__ R) {
  __shared__ double accd[512];
  __shared__ float Wf[8192];
  __shared__ int   li[KSEL];
  __shared__ float lv[KSEL];
  int p = blockIdx.x;
  int lg = (p & 7) * 96 + (p >> 3);
  int s = lg / 24; int r = lg % 24; int c = r >> 3; int band = r & 7;
  int row0 = band * 8;
  int tid = threadIdx.x;
  for (int e = tid; e < 512; e += 256) accd[e] = 0.0;
  for (int e = tid; e < 8192; e += 256) {
    int a = e >> 6, k2 = e & 63;
    Wf[e] = Wg[(a * 3 + c) * 64 + k2];
  }
  for (int e = tid; e < KSEL; e += 256) {
    li[e] = nzidx[s * KSEL + e];
    lv[e] = nzval[s * KSEL + e];
  }
  __syncthreads();
  int slot = tid >> 3, kw = tid & 7;
  for (int e = slot; e < KSEL; e += 32) {
    int idx = li[e];
    int a = (int)((unsigned)idx / 3249u);
    int pp = idx - a * 3249;
    int y = (int)((unsigned)pp / 57u);
    int x = pp - y * 57;
    int dy = y - row0;
    if (dy < -7 || dy > 7) continue;
    double val = (double)lv[e];
    const float* wp = Wf + (a << 6) + kw;
#pragma unroll
    for (int kh = 0; kh < 8; ++kh) {
      int rr = dy + kh;
      if ((unsigned)rr < 8u)
        __hip_atomic_fetch_add(&accd[(rr << 6) + x + kw],
                               val * (double)wp[kh << 3],
                               __ATOMIC_RELAXED, __HIP_MEMORY_SCOPE_WORKGROUP);
    }
  }
  __syncthreads();
  const float* Yb = Y + (((size_t)(s * CCH + c)) << 12) + (row0 << 6);
  float* Rb = R + (((size_t)(s * CCH + c)) << 12) + (row0 << 6);
  for (int e = tid; e < 512; e += 256)
    Rb[e] = (float)(accd[e] - (double)Yb[e]);
}

// ---------------------------------------------------------------------------
// HT = xprev - Dt(R) in f32 (classification), fused L1 hist. RECON=true:
// xprev reconstructed in-place from HT's previous (patched-exact) value via
// (tauPrev, cutPrev); same-thread read-then-write of HT[xo] (1:1 ownership).
// RECON=false (it0): xprev = X0[xo]. Core math identical to r14-16 verified.
// ---------------------------------------------------------------------------
template <typename TR, bool RECON>
__global__ __launch_bounds__(256) void convDt_k(const TR* __restrict__ R,
    const float* __restrict__ Wt2f, const float* Xsrc, float* HT,
    const unsigned* __restrict__ tauArr, const int* __restrict__ cutArr,
    unsigned* __restrict__ g1) {
  __shared__ float Rl[3][15][72];
  __shared__ unsigned hh[1024];
  int p = blockIdx.x;
  int lg = (p & 7) * 512 + (p >> 3);
  int b = lg >> 7; int rem = lg & 127; int ag = rem >> 3; int by = rem & 7;
  int row0 = by * 8;
  int a0 = ag * 8;
  int tid = threadIdx.x;
  unsigned tt = 0; int co = 0;
  if constexpr (RECON) { tt = tauArr[b]; co = cutArr[b]; }
  for (int e = tid; e < 1024; e += 256) hh[e] = 0;
  for (int e = tid; e < 3 * 15 * 72; e += 256) {
    int c = e / (15 * 72); int r2 = e - c * (15 * 72);
    int rr = r2 / 72; int cc = r2 - rr * 72;
    int gr = row0 + rr;
    float v = 0.0f;
    if (cc < OWW && gr < OHH)
      v = (float)R[((size_t)(b * CCH + c) << 12) + (gr << 6) + cc];
    Rl[c][rr][cc] = v;
  }
  __syncthreads();
  int x = tid & 63, yg = tid >> 6;
  int yb = yg * 2;
  float acc[8][2];
#pragma unroll
  for (int aa = 0; aa < 8; ++aa) { acc[aa][0] = 0.0f; acc[aa][1] = 0.0f; }

#pragma unroll 1
  for (int c = 0; c < 3; ++c) {
#pragma unroll 1
    for (int j = 0; j < 8; ++j) {
      float rw[9];
#pragma unroll
      for (int r = 0; r < 9; ++r) rw[r] = Rl[c][yb + r][x + j];
#pragma unroll
      for (int i = 0; i < 8; ++i) {
        const float* wp = Wt2f + ((c * 8 + i) * 8 + j) * 128 + a0;
#pragma unroll
        for (int aa = 0; aa < 8; ++aa) {
          float w = wp[aa];
          acc[aa][0] = fmaf(rw[i + 0], w, acc[aa][0]);
          acc[aa][1] = fmaf(rw[i + 1], w, acc[aa][1]);
        }
      }
    }
  }
  if (x < XW) {
#pragma unroll
    for (int ty = 0; ty < 2; ++ty) {
      int yy = row0 + yb + ty;
      if (yy < XH) {
#pragma unroll
        for (int aa = 0; aa < 8; ++aa) {
          size_t xo = (size_t)(b * ATOMS + a0 + aa) * PIX + yy * XW + x;
          float xprev;
          if constexpr (RECON) {
            float hp = HT[xo];                      // prev patched value
            unsigned hu = __float_as_uint(hp) & 0x7fffffffu;
            int il = (a0 + aa) * PIX + yy * XW + x;
            xprev = (hu > tt || (hu == tt && il <= co)) ? hp : 0.0f;
          } else {
            xprev = Xsrc[xo];
          }
          float fv = xprev - acc[aa][ty];
          HT[xo] = fv;
          unsigned u = __float_as_uint(fv) & 0x7fffffffu;
          unsigned bin = u >> 20;
          atomicAdd(&hh[bin >> 1], 1u << ((bin & 1) << 4));
        }
      }
    }
  }
  __syncthreads();
  unsigned* gp = g1 + (size_t)b * 2048;
  for (int e = tid; e < 1024; e += 256) {
    unsigned v = hh[e];
    unsigned lo = v & 0xffffu, hi = v >> 16;
    if (lo) atomicAdd(&gp[2 * e], lo);
    if (hi) atomicAdd(&gp[2 * e + 1], hi);
  }
}

// ---------------------------------------------------------------------------
// histwrite_k (fused pass3 in last block): 2-bin safety band classify,
// candidate gather + exact f64 re-eval (xprev: X0 at it0, else 0 + nz-hash
// correction in the last block). Last block per sample (done-counter +
// device fences, no-spin) runs the full select, patches HT (!FINAL) or
// writes Xout candidates (FINAL), emits nz list, resets per-sample state.
// ---------------------------------------------------------------------------
union ShU {
  int lidx[LCAP];                                        // 24KB scan
  struct { int hidx[4096]; float hval[4096]; } hs;       // 32KB correction
  struct { unsigned h[2048]; int eqidx[1024];
           int kidx[2048]; float kval[2048]; } p3;       // 28KB select
};

template <typename TR, bool RECON, bool FINAL>
__global__ __launch_bounds__(256) void histwrite_k(float* HT,
    unsigned* __restrict__ g1, const TR* __restrict__ R,
    const float* __restrict__ Wcand, const float* __restrict__ Xp,
    int* __restrict__ cand, int* __restrict__ candcnt,
    float* __restrict__ candval, unsigned* __restrict__ done,
    float* __restrict__ Xo, int* __restrict__ nzidx, float* __restrict__ nzval,
    unsigned* __restrict__ tauArr, int* __restrict__ cutArr) {
  __shared__ ShU u;
  __shared__ unsigned part[256];
  __shared__ int lcnt, lbase, b1_sh, islast;
  int tid = threadIdx.x;
  int s = blockIdx.x >> 5;
  int chunk = blockIdx.x & 31;
  unsigned* hg1 = g1 + (size_t)s * 2048;
  unsigned psum = 0;
#pragma unroll
  for (int e = 0; e < 8; ++e) psum += hg1[tid * 8 + e];
  part[tid] = psum;
  if (tid == 0) lcnt = 0;
  __syncthreads();
  if (tid == 0) {
    int Kv = KSEL;
    unsigned cumBefore = 0;
    int bsel = 0;
    for (int q = 255; q >= 0; --q) {
      unsigned ps = part[q];
      if ((int)(cumBefore + ps) >= Kv) {
        for (int e = q * 8 + 7;; --e) {
          unsigned c2 = cumBefore + hg1[e];
          if ((int)c2 >= Kv) { bsel = e; break; }
          cumBefore = c2;
        }
        break;
      }
      cumBefore += ps;
    }
    b1_sh = bsel;
  }
  __syncthreads();
  unsigned blo = (unsigned)(b1_sh >= 2 ? b1_sh - 2 : 0);
  size_t sbase = (size_t)s * NPS;
  const uint4* U4 = (const uint4*)(HT + sbase);
  for (int i4 = chunk * 256 + tid; i4 < NPS / 4; i4 += 32 * 256) {
    uint4 v = U4[i4];
    unsigned uu[4] = {v.x, v.y, v.z, v.w};
    int m = 0;
#pragma unroll
    for (int t = 0; t < 4; ++t) {
      unsigned uv = uu[t] & 0x7fffffffu;
      if ((uv >> 20) >= blo) {
        m |= 1 << t;
        int pos = atomicAdd(&lcnt, 1);
        if (pos < LCAP) u.lidx[pos] = i4 * 4 + t;
      }
    }
    if constexpr (FINAL) {
      if (m == 0) {
        ((float4*)(Xo + sbase))[i4] = make_float4(0.0f, 0.0f, 0.0f, 0.0f);
      } else {
#pragma unroll
        for (int t = 0; t < 4; ++t)
          if (!(m & (1 << t))) Xo[sbase + i4 * 4 + t] = 0.0f;
      }
    }
  }
  __syncthreads();
  if (tid == 0) {
    int nn = lcnt < LCAP ? lcnt : LCAP;
    lbase = atomicAdd(&candcnt[s], nn);
  }
  __syncthreads();
  int nn = lcnt < LCAP ? lcnt : LCAP;
  const TR* Rb = R + ((size_t)(s * 3) << 12);
  for (int e = tid; e < nn; e += 256) {
    int i = u.lidx[e];
    int g = lbase + e;
    int a = (int)((unsigned)i / 3249u);
    int p = i - a * 3249;
    int y = (int)((unsigned)p / 57u);
    int x = p - y * 57;
    double xprev = RECON ? 0.0 : (double)Xp[sbase + i];
    const float* wa = Wcand + (a << 8);
    double acc = 0.0;
    for (int c = 0; c < 3; ++c) {
#pragma unroll
      for (int ii = 0; ii < 8; ++ii) {
        const TR* rrow = Rb + (c << 12) + ((y + ii) << 6) + x;
        const float* wrow = wa + (c * 8 + ii) * 8;
#pragma unroll
        for (int jj = 0; jj < 8; ++jj)
          acc = fma((double)rrow[jj], (double)wrow[jj], acc);
      }
    }
    float cf = (float)(xprev - acc);
    if (g < CANDCAP) {
      cand[s * CANDCAP + g] = i;
      candval[s * CANDCAP + g] = cf;
    }
  }
  // ---- last-block handshake ----
  __threadfence();
  __syncthreads();
  if (tid == 0) {
    unsigned prev = atomicAdd(&done[s], 1u);
    islast = (prev == 31);
  }
  __syncthreads();
  if (!islast) return;
  __threadfence();

  // =================== fused pass3 (last block only) ===================
  int t = tid;
  int n = candcnt[s];
  if (n > CANDCAP) n = CANDCAP;
  const int* cs = cand + s * CANDCAP;
  float* cvp = candval + s * CANDCAP;
  // correction: add exact prev-keep xprev values (nz list) to candvals
  if constexpr (RECON) {
    for (int e = t; e < 4096; e += 256) u.hs.hidx[e] = -1;
    __syncthreads();
    for (int e = t; e < KSEL; e += 256) {
      int idx = nzidx[s * KSEL + e];
      float v = nzval[s * KSEL + e];
      int slot = idx & 4095;
      while (true) {
        int old = atomicCAS(&u.hs.hidx[slot], -1, idx);
        if (old == -1) { u.hs.hval[slot] = v; break; }
        slot = (slot + 1) & 4095;
      }
    }
    __syncthreads();
    for (int e = t; e < n; e += 256) {
      int i = cs[e];
      int slot = i & 4095;
      while (true) {
        int h = u.hs.hidx[slot];
        if (h == i) { cvp[e] += u.hs.hval[slot]; break; }
        if (h == -1) break;
        slot = (slot + 1) & 4095;
      }
    }
    __syncthreads();
  }
  // select: 3-level radix over corrected candvals (verified r16 logic)
  __shared__ int eqn, kcnt;
  __shared__ unsigned tau_sh;
  __shared__ int k3_sh, cutoff_sh, b1x_sh, k1_sh, b2_sh, k2_sh;
  for (int e = t; e < 2048; e += 256) u.p3.h[e] = 0;
  if (t == 0) { eqn = 0; kcnt = 0; }
  __syncthreads();
  for (int e = t; e < n; e += 256) {
    unsigned uv = __float_as_uint(cvp[e]) & 0x7fffffffu;
    atomicAdd(&u.p3.h[uv >> 20], 1u);
  }
  __syncthreads();
  unsigned s1 = 0;
#pragma unroll
  for (int e = 0; e < 8; ++e) s1 += u.p3.h[t * 8 + e];
  part[t] = s1;
  __syncthreads();
  if (t == 0) {
    int Kv = KSEL;
    unsigned cumBefore = 0;
    int bsel = 0;
    for (int q = 255; q >= 0; --q) {
      unsigned ps = part[q];
      if ((int)(cumBefore + ps) >= Kv) {
        for (int e = q * 8 + 7;; --e) {
          unsigned c2 = cumBefore + u.p3.h[e];
          if ((int)c2 >= Kv) { bsel = e; break; }
          cumBefore = c2;
        }
        break;
      }
      cumBefore += ps;
    }
    b1x_sh = bsel;
    k1_sh = KSEL - (int)cumBefore;
  }
  __syncthreads();
  unsigned b1x = (unsigned)b1x_sh;
  for (int e = t; e < 1024; e += 256) u.p3.h[e] = 0;
  __syncthreads();
  for (int e = t; e < n; e += 256) {
    unsigned uv = __float_as_uint(cvp[e]) & 0x7fffffffu;
    if ((uv >> 20) == b1x) atomicAdd(&u.p3.h[(uv >> 10) & 1023], 1u);
  }
  __syncthreads();
  part[t] = u.p3.h[t*4] + u.p3.h[t*4+1] + u.p3.h[t*4+2] + u.p3.h[t*4+3];
  __syncthreads();
  if (t == 0) {
    int Kv = k1_sh;
    unsigned cumBefore = 0;
    int bsel = 0;
    for (int q = 255; q >= 0; --q) {
      unsigned ps = part[q];
      if ((int)(cumBefore + ps) >= Kv) {
        for (int e = q * 4 + 3;; --e) {
          unsigned c2 = cumBefore + u.p3.h[e];
          if ((int)c2 >= Kv) { bsel = e; break; }
          cumBefore = c2;
        }
        break;
      }
      cumBefore += ps;
    }
    b2_sh = bsel;
    k2_sh = Kv - (int)cumBefore;
  }
  __syncthreads();
  for (int e = t; e < 1024; e += 256) u.p3.h[e] = 0;
  __syncthreads();
  unsigned pre21 = (b1x << 10) | (unsigned)b2_sh;
  for (int e = t; e < n; e += 256) {
    unsigned uv = __float_as_uint(cvp[e]) & 0x7fffffffu;
    if ((uv >> 10) == pre21) atomicAdd(&u.p3.h[uv & 1023], 1u);
  }
  __syncthreads();
  if (t == 0) {
    int Kv = k2_sh;
    unsigned cumBefore = 0;
    int b3 = 0;
    for (int e = 1023; e >= 0; --e) {
      unsigned c2 = cumBefore + u.p3.h[e];
      if ((int)c2 >= Kv) { b3 = e; break; }
      cumBefore = c2;
    }
    tau_sh = (pre21 << 10) | (unsigned)b3;
    k3_sh = Kv - (int)cumBefore;
  }
  __syncthreads();
  unsigned tau = tau_sh;
  for (int e = t; e < n; e += 256) {
    unsigned uv = __float_as_uint(cvp[e]) & 0x7fffffffu;
    if (uv == tau) {
      int pos = atomicAdd(&eqn, 1);
      if (pos < 1024) u.p3.eqidx[pos] = cs[e];
    }
  }
  __syncthreads();
  if (t == 0) {
    int m = eqn < 1024 ? eqn : 1024;
    int k3 = k3_sh;
    int cutoff;
    if (k3 >= m) {
      cutoff = 0x7fffffff;
    } else {
      int last = -1;
      for (int r = 0; r < k3; ++r) {
        int mn = 0x7fffffff;
        for (int q = 0; q < m; ++q) {
          int v = u.p3.eqidx[q];
          if (v > last && v < mn) mn = v;
        }
        last = mn;
      }
      cutoff = last;
    }
    cutoff_sh = cutoff;
  }
  __syncthreads();
  int co = cutoff_sh;
  for (int e = t; e < n; e += 256) {
    int i = cs[e];
    float cf = cvp[e];
    unsigned uv = __float_as_uint(cf) & 0x7fffffffu;
    bool keep = (uv > tau) || (uv == tau && i <= co);
    if constexpr (FINAL) {
      Xo[sbase + i] = keep ? cf : 0.0f;
    } else {
      HT[sbase + i] = cf;                 // patch: exact value for next iter
      if (keep) {
        int pos = atomicAdd(&kcnt, 1);
        if (pos < 2048) { u.p3.kidx[pos] = i; u.p3.kval[pos] = cf; }
      }
    }
  }
  __syncthreads();
  if constexpr (!FINAL) {
    int kn = kcnt < KSEL ? kcnt : KSEL;
    for (int e = t; e < kn; e += 256) {
      nzidx[s * KSEL + e] = u.p3.kidx[e];
      nzval[s * KSEL + e] = u.p3.kval[e];
    }
    if (t == 0) { tauArr[s] = tau; cutArr[s] = co; }
  }
  // reset per-sample state
  for (int e = t; e < 2048; e += 256) hg1[e] = 0;
  if (t == 0) { candcnt[s] = 0; done[s] = 0; }
}

extern "C" void kernel_launch(void* const* d_in, const int* in_sizes, int n_in,
                              void* d_out, int out_size, void* d_ws, size_t ws_size,
                              hipStream_t stream) {
  const float* Y  = (const float*)d_in[0];
  const float* X0 = (const float*)d_in[1];
  const float* Wg = (const float*)d_in[2];
  float* Xout = (float*)d_out;

  double* WDd  = (double*)d_ws;                        // NW f64
  float* Wt2f  = (float*)(WDd + NW);                   // NW f32
  float* Wcand = Wt2f + NW;                            // NWC f32
  float* HT   = Wcand + NWC;                           // NTOT f32
  float* Rbuf = HT + NTOT;                             // RTOT f32
  double* Rd  = (double*)(Rbuf + RTOT);                // RTOT f64
  unsigned* g1 = (unsigned*)(Rd + RTOT);               // 32*2048
  int* candcnt = (int*)(g1 + 32 * 2048);               // 32
  unsigned* done = (unsigned*)(candcnt + 32);          // 32
  int* cand = (int*)(done + 32);                       // 32*CANDCAP
  float* candval = (float*)(cand + 32 * CANDCAP);      // 32*CANDCAP
  int* nzidx = (int*)(candval + 32 * CANDCAP);         // 32*KSEL
  float* nzval = (float*)(nzidx + 32 * KSEL);          // 32*KSEL
  unsigned* tauArr = (unsigned*)(nzval + 32 * KSEL);   // 32
  int* cutArr = (int*)(tauArr + 32);                   // 32

  prep_k<<<dim3((RTOT + 255) / 256), dim3(256), 0, stream>>>(
      Wg, WDd, Wt2f, Wcand, Y, Rd, g1);

  for (int it = 0; it < 3; ++it) {
    if (it == 0) {
      convD_k<<<dim3(2048), dim3(256), 0, stream>>>(X0, WDd, Rd);
      convDt_k<double, false><<<dim3(4096), dim3(256), 0, stream>>>(
          Rd, Wt2f, X0, HT, tauArr, cutArr, g1);
      histwrite_k<double, false, false><<<dim3(BATCH * 32), dim3(256), 0, stream>>>(
          HT, g1, Rd, Wcand, X0, cand, candcnt, candval, done,
          Xout, nzidx, nzval, tauArr, cutArr);
    } else {
      convD_sparse_k<<<dim3(BATCH * CCH * 8), dim3(256), 0, stream>>>(
          Wg, nzidx, nzval, Y, Rbuf);
      convDt_k<float, true><<<dim3(4096), dim3(256), 0, stream>>>(
          Rbuf, Wt2f, HT, HT, tauArr, cutArr, g1);
      if (it == 1) {
        histwrite_k<float, true, false><<<dim3(BATCH * 32), dim3(256), 0, stream>>>(
            HT, g1, Rbuf, Wcand, X0, cand, candcnt, candval, done,
            Xout, nzidx, nzval, tauArr, cutArr);
      } else {
        histwrite_k<float, true, true><<<dim3(BATCH * 32), dim3(256), 0, stream>>>(
            HT, g1, Rbuf, Wcand, X0, cand, candcnt, candval, done,
            Xout, nzidx, nzval, tauArr, cutArr);
      }
    }
  }
}

// Round 18
// 949.909 us; speedup vs baseline: 1.3973x; 1.3973x over previous
//
#include <hip/hip_runtime.h>

#define BATCH 32
#define ATOMS 128
#define CCH 3
#define XH 57
#define XW 57
#define OHH 64
#define OWW 64
#define KSEL 2000
#define PIX (XH*XW)            // 3249
#define NPS (ATOMS*PIX)        // 415872
#define NTOT (BATCH*NPS)       // 13307904
#define RPS (CCH*OHH*OWW)      // 12288
#define RTOT (BATCH*RPS)       // 393216
#define CANDCAP 32768
#define NW 24576
#define NWC 32768              // Wcand padded: 128 atoms x 256
#define WCAP 1536              // per-wave candidate cap (4 waves -> 6144/block)
#define ZWORDS (32*2048 + 32)  // g1 + candcnt

// ---------------------------------------------------------------------------
// Prep (once): WDd f64 (convD), Wt2f f32 (convDt), Wcand f32 (exact dot,
// 192 contiguous per atom), Rd = -Y, zero g1/candcnt.
// ---------------------------------------------------------------------------
__global__ __launch_bounds__(256) void prep_k(const float* __restrict__ Wg,
    double* __restrict__ WDd, float* __restrict__ Wt2f,
    float* __restrict__ Wcand, const float* __restrict__ Y,
    double* __restrict__ Rd, unsigned* __restrict__ zbuf) {
  int e = blockIdx.x * 256 + threadIdx.x;
  if (e < NW) {
    {
      int kw = e & 7; int t = e >> 3; int c = t % 3; t /= 3; int kh = t & 7; int a = t >> 3;
      WDd[e] = (double)Wg[(a*3 + c)*64 + kh*8 + kw];
    }
    {
      int a = e & 127; int t = e >> 7; int j = t & 7; int i = (t >> 3) & 7; int c = t >> 6;
      Wt2f[e] = Wg[(a*3 + c)*64 + j*8 + i];   // [c][i][j][a], exact f32
    }
  }
  if (e < NWC) {
    int a = e >> 8, r = e & 255;
    float v = 0.0f;
    if (r < 192) {
      int c = r >> 6, ii = (r >> 3) & 7, jj = r & 7;
      v = Wg[(a*3 + c)*64 + jj*8 + ii];       // Wcand[a][(c*8+ii)*8+jj]=W[a,c,jj,ii]
    }
    Wcand[e] = v;
  }
  if (e < RTOT) Rd[e] = -(double)Y[e];
  if (e < ZWORDS) zbuf[e] = 0;
}

// ---------------------------------------------------------------------------
// DENSE R += D(X) (iteration 0 only). Verified r11+ version, unchanged.
// ---------------------------------------------------------------------------
__global__ __launch_bounds__(256) void convD_k(const float* __restrict__ X,
    const double* __restrict__ WDd, double* __restrict__ Rd) {
  __shared__ double Xs[4][11][72];            // 25344 B
  int p = blockIdx.x;
  int lg = (p & 7) * 256 + (p >> 3);          // bijective: 2048 = 8*256
  int b = lg >> 6; int rem = lg & 63;
  int band = rem >> 2, quarter = rem & 3;
  int row0 = band * 4;
  int a_base = quarter * 32;
  int tid = threadIdx.x;
  int ox = tid & 63;
  int wv = __builtin_amdgcn_readfirstlane(tid >> 6);
  const float* Xb = X + (size_t)b * NPS;

  double acc[4][3];
#pragma unroll
  for (int ty = 0; ty < 4; ++ty)
#pragma unroll
    for (int c = 0; c < 3; ++c) acc[ty][c] = 0.0;

  for (int ch = 0; ch < 8; ++ch) {
    __syncthreads();
    for (int e = tid; e < 4 * 11 * 72; e += 256) {
      int ai = e / 792; int rem2 = e - ai * 792;
      int r = rem2 / 72; int ss = rem2 - r * 72;
      int gy = row0 - 7 + r;
      int xcol = ss - 7;
      int a = a_base + ch * 4 + ai;
      float v = 0.0f;
      if ((unsigned)xcol < (unsigned)XW && (unsigned)gy < (unsigned)XH)
        v = Xb[a * PIX + gy * XW + xcol];
      Xs[ai][r][ss] = (double)v;
    }
    __syncthreads();
    {
      int a = a_base + ch * 4 + wv;
      const double* Wa = WDd + a * 192;       // [kh][c][kw]
#pragma unroll
      for (int r = 0; r < 11; ++r) {
        int gy = row0 - 7 + r;
        if ((unsigned)gy >= (unsigned)XH) continue;   // uniform
        double xd[8];
#pragma unroll
        for (int t = 0; t < 8; ++t) xd[t] = Xs[wv][r][ox + t];
#pragma unroll
        for (int ty = 0; ty < 4; ++ty) {
          int kh = ty + 7 - r;
          if ((unsigned)kh < 8u) {
            const double* Wk = Wa + kh * 24;
#pragma unroll
            for (int kw = 0; kw < 8; ++kw) {
              acc[ty][0] = fma(xd[7 - kw], Wk[kw],      acc[ty][0]);
              acc[ty][1] = fma(xd[7 - kw], Wk[8 + kw],  acc[ty][1]);
              acc[ty][2] = fma(xd[7 - kw], Wk[16 + kw], acc[ty][2]);
            }
          }
        }
      }
    }
  }
#pragma unroll
  for (int ty = 0; ty < 4; ++ty) {
    int oy = row0 + ty;
#pragma unroll
    for (int c = 0; c < 3; ++c)
      atomicAdd(&Rd[((size_t)(b * CCH + c) << 12) + (oy << 6) + ox], acc[ty][c]);
  }
}

// ---------------------------------------------------------------------------
// SPARSE R = D(X) - Y (iterations 1,2). Verified, unchanged.
// ---------------------------------------------------------------------------
__global__ __launch_bounds__(256) void convD_sparse_k(const float* __restrict__ Wg,
    const int* __restrict__ nzidx, const float* __restrict__ nzval,
    const float* __restrict__ Y, float* __restrict__ R) {
  __shared__ double accd[512];       // [rr][ox]
  __shared__ float Wf[8192];         // [a][kh][kw] for this c
  __shared__ int   li[KSEL];
  __shared__ float lv[KSEL];
  int p = blockIdx.x;
  int lg = (p & 7) * 96 + (p >> 3);  // bijective: 768 = 8*96
  int s = lg / 24; int r = lg % 24; int c = r >> 3; int band = r & 7;
  int row0 = band * 8;
  int tid = threadIdx.x;
  for (int e = tid; e < 512; e += 256) accd[e] = 0.0;
  for (int e = tid; e < 8192; e += 256) {
    int a = e >> 6, k2 = e & 63;
    Wf[e] = Wg[(a * 3 + c) * 64 + k2];
  }
  for (int e = tid; e < KSEL; e += 256) {
    li[e] = nzidx[s * KSEL + e];
    lv[e] = nzval[s * KSEL + e];
  }
  __syncthreads();
  int slot = tid >> 3, kw = tid & 7;
  for (int e = slot; e < KSEL; e += 32) {
    int idx = li[e];
    int a = (int)((unsigned)idx / 3249u);
    int pp = idx - a * 3249;
    int y = (int)((unsigned)pp / 57u);
    int x = pp - y * 57;
    int dy = y - row0;
    if (dy < -7 || dy > 7) continue;
    double val = (double)lv[e];
    const float* wp = Wf + (a << 6) + kw;
#pragma unroll
    for (int kh = 0; kh < 8; ++kh) {
      int rr = dy + kh;
      if ((unsigned)rr < 8u)
        __hip_atomic_fetch_add(&accd[(rr << 6) + x + kw],
                               val * (double)wp[kh << 3],
                               __ATOMIC_RELAXED, __HIP_MEMORY_SCOPE_WORKGROUP);
    }
  }
  __syncthreads();
  const float* Yb = Y + (((size_t)(s * CCH + c)) << 12) + (row0 << 6);
  float* Rb = R + (((size_t)(s * CCH + c)) << 12) + (row0 << 6);
  for (int e = tid; e < 512; e += 256)
    Rb[e] = (float)(accd[e] - (double)Yb[e]);
}

// ---------------------------------------------------------------------------
// HT~ = Xprev - Dt(R) in f32 (classification only), fused L1 hist.
// r14-r16 verified, unchanged.
// ---------------------------------------------------------------------------
template <typename TR>
__global__ __launch_bounds__(256) void convDt_k(const TR* __restrict__ R,
    const float* __restrict__ Wt2f, const float* __restrict__ Xprev,
    float* __restrict__ HT, unsigned* __restrict__ g1) {
  __shared__ float Rl[3][15][72];
  __shared__ unsigned hh[1024];      // packed: 2 u16 bins per word
  int p = blockIdx.x;
  int lg = (p & 7) * 512 + (p >> 3);  // bijective: 4096 = 8*512
  int b = lg >> 7; int rem = lg & 127; int ag = rem >> 3; int by = rem & 7;
  int row0 = by * 8;
  int a0 = ag * 8;
  int tid = threadIdx.x;
  for (int e = tid; e < 1024; e += 256) hh[e] = 0;
  for (int e = tid; e < 3 * 15 * 72; e += 256) {
    int c = e / (15 * 72); int r2 = e - c * (15 * 72);
    int rr = r2 / 72; int cc = r2 - rr * 72;
    int gr = row0 + rr;
    float v = 0.0f;
    if (cc < OWW && gr < OHH)
      v = (float)R[((size_t)(b * CCH + c) << 12) + (gr << 6) + cc];
    Rl[c][rr][cc] = v;
  }
  __syncthreads();
  int x = tid & 63, yg = tid >> 6;
  int yb = yg * 2;
  float acc[8][2];
#pragma unroll
  for (int aa = 0; aa < 8; ++aa) { acc[aa][0] = 0.0f; acc[aa][1] = 0.0f; }

#pragma unroll 1
  for (int c = 0; c < 3; ++c) {
#pragma unroll 1
    for (int j = 0; j < 8; ++j) {
      float rw[9];
#pragma unroll
      for (int r = 0; r < 9; ++r) rw[r] = Rl[c][yb + r][x + j];
#pragma unroll
      for (int i = 0; i < 8; ++i) {
        const float* wp = Wt2f + ((c * 8 + i) * 8 + j) * 128 + a0;  // uniform
#pragma unroll
        for (int aa = 0; aa < 8; ++aa) {
          float w = wp[aa];
          acc[aa][0] = fmaf(rw[i + 0], w, acc[aa][0]);
          acc[aa][1] = fmaf(rw[i + 1], w, acc[aa][1]);
        }
      }
    }
  }
  if (x < XW) {
#pragma unroll
    for (int ty = 0; ty < 2; ++ty) {
      int yy = row0 + yb + ty;
      if (yy < XH) {
#pragma unroll
        for (int aa = 0; aa < 8; ++aa) {
          size_t xo = (size_t)(b * ATOMS + a0 + aa) * PIX + yy * XW + x;
          float fv = Xprev[xo] - acc[aa][ty];
          HT[xo] = fv;
          unsigned u = __float_as_uint(fv) & 0x7fffffffu;
          unsigned bin = u >> 20;
          atomicAdd(&hh[bin >> 1], 1u << ((bin & 1) << 4));
        }
      }
    }
  }
  __syncthreads();
  unsigned* gp = g1 + (size_t)b * 2048;
  for (int e = tid; e < 1024; e += 256) {
    unsigned v = hh[e];
    unsigned lo = v & 0xffffu, hi = v >> 16;
    if (lo) atomicAdd(&gp[2 * e], lo);
    if (hi) atomicAdd(&gp[2 * e + 1], hi);
  }
}

// ---------------------------------------------------------------------------
// histwrite_k (recompute fused): 2-bin safety band classify; candidate
// gather uses PER-WAVE counters/lists (cuts single-address LDS atomic
// serialization ~4x vs one block counter); candidate lanes skip the store
// (Xo[i] still holds prev X at it>=1; pass3 writes every candidate), then
// exact f64 re-eval from Wcand (contiguous) + Xp.
// ---------------------------------------------------------------------------
template <typename TR>
__global__ __launch_bounds__(256) void histwrite_k(const float* __restrict__ HT,
    const unsigned* __restrict__ g1, const TR* __restrict__ R,
    const float* __restrict__ Wcand, const float* Xp,
    int* __restrict__ cand, int* __restrict__ candcnt,
    float* __restrict__ candval, float* Xo) {
  __shared__ unsigned part[256];
  __shared__ int lidx[4][WCAP];
  __shared__ int wcnt[4];
  __shared__ int lbase, b1_sh;
  int tid = threadIdx.x;
  int wv = tid >> 6;
  int s = blockIdx.x >> 5;
  int chunk = blockIdx.x & 31;
  const unsigned* hg1 = g1 + (size_t)s * 2048;
  unsigned psum = 0;
#pragma unroll
  for (int e = 0; e < 8; ++e) psum += hg1[tid * 8 + e];
  part[tid] = psum;
  if (tid < 4) wcnt[tid] = 0;
  __syncthreads();
  if (tid == 0) {
    int Kv = KSEL;
    unsigned cumBefore = 0;
    int bsel = 0;
    for (int q = 255; q >= 0; --q) {
      unsigned ps = part[q];
      if ((int)(cumBefore + ps) >= Kv) {
        for (int e = q * 8 + 7;; --e) {
          unsigned c2 = cumBefore + hg1[e];
          if ((int)c2 >= Kv) { bsel = e; break; }
          cumBefore = c2;
        }
        break;
      }
      cumBefore += ps;
    }
    b1_sh = bsel;
  }
  __syncthreads();
  unsigned blo = (unsigned)(b1_sh >= 2 ? b1_sh - 2 : 0);
  size_t sbase = (size_t)s * NPS;
  const uint4* U4 = (const uint4*)(HT + sbase);
  float4* X4 = (float4*)(Xo + sbase);
  for (int i4 = chunk * 256 + tid; i4 < NPS / 4; i4 += 32 * 256) {
    uint4 v = U4[i4];
    unsigned uu[4] = {v.x, v.y, v.z, v.w};
    int m = 0;
#pragma unroll
    for (int t = 0; t < 4; ++t) {
      unsigned u = uu[t] & 0x7fffffffu;
      if ((u >> 20) >= blo) {
        m |= 1 << t;
        int pos = atomicAdd(&wcnt[wv], 1);
        if (pos < WCAP) lidx[wv][pos] = i4 * 4 + t;
      }
    }
    if (m == 0) {
      X4[i4] = make_float4(0.0f, 0.0f, 0.0f, 0.0f);
    } else {
#pragma unroll
      for (int t = 0; t < 4; ++t)
        if (!(m & (1 << t))) Xo[sbase + i4 * 4 + t] = 0.0f;
    }
  }
  __syncthreads();
  // merge per-wave counts -> block total, reserve global slice
  int wn[4], woff[4];
  {
    int acc2 = 0;
#pragma unroll
    for (int q = 0; q < 4; ++q) {
      wn[q] = wcnt[q] < WCAP ? wcnt[q] : WCAP;
      woff[q] = acc2;
      acc2 += wn[q];
    }
    if (tid == 0) lbase = atomicAdd(&candcnt[s], acc2);
  }
  __syncthreads();
  // exact f64 re-evaluation of this block's candidates
  const TR* Rb = R + ((size_t)(s * 3) << 12);
  int ntot = wn[0] + wn[1] + wn[2] + wn[3];
  for (int e = tid; e < ntot; e += 256) {
    int q = 0, eo = e;
    while (q < 3 && eo >= wn[q]) { eo -= wn[q]; ++q; }
    int i = lidx[q][eo];
    int g = lbase + woff[q] + eo;
    int a = (int)((unsigned)i / 3249u);
    int p = i - a * 3249;
    int y = (int)((unsigned)p / 57u);
    int x = p - y * 57;
    double xprev = (double)Xp[sbase + i];     // candidate lane: never zeroed
    const float* wa = Wcand + (a << 8);
    double acc = 0.0;
    for (int c = 0; c < 3; ++c) {
#pragma unroll
      for (int ii = 0; ii < 8; ++ii) {
        const TR* rrow = Rb + (c << 12) + ((y + ii) << 6) + x;
        const float* wrow = wa + (c * 8 + ii) * 8;
#pragma unroll
        for (int jj = 0; jj < 8; ++jj)
          acc = fma((double)rrow[jj], (double)wrow[jj], acc);
      }
    }
    float cf = (float)(xprev - acc);
    if (g < CANDCAP) {
      cand[s * CANDCAP + g] = i;
      candval[s * CANDCAP + g] = cf;
    }
  }
}

// ---------------------------------------------------------------------------
// pass3_k: exact 3-level radix select over candidate values (self-computed
// L1 hist), tie resolution by lowest index, Xout fixup (every candidate),
// nz-list emit, per-sample g1/candcnt reset. r16 verified, unchanged.
// ---------------------------------------------------------------------------
__global__ __launch_bounds__(256) void pass3_k(const int* __restrict__ cand,
    int* __restrict__ candcnt, const float* __restrict__ candval,
    unsigned* __restrict__ g1, float* __restrict__ Xo,
    int* __restrict__ nzidx, float* __restrict__ nzval, int emit) {
  int s = blockIdx.x;
  __shared__ unsigned h[2048];
  __shared__ unsigned part[256];
  __shared__ int eqidx[1024];
  __shared__ int kidx[2048];
  __shared__ float kval[2048];
  __shared__ int eqn, kcnt;
  __shared__ unsigned tau_sh;
  __shared__ int k3_sh, cutoff_sh, b1_sh, k1_sh, b2_sh, k2_sh;
  int t = threadIdx.x;
  int n = candcnt[s];
  if (n > CANDCAP) n = CANDCAP;
  const int* cs = cand + s * CANDCAP;
  const float* cv = candval + s * CANDCAP;
  for (int e = t; e < 2048; e += 256) h[e] = 0;
  if (t == 0) { eqn = 0; kcnt = 0; }
  __syncthreads();
  for (int e = t; e < n; e += 256) {
    unsigned u = __float_as_uint(cv[e]) & 0x7fffffffu;
    atomicAdd(&h[u >> 20], 1u);
  }
  __syncthreads();
  unsigned s1 = 0;
#pragma unroll
  for (int e = 0; e < 8; ++e) s1 += h[t * 8 + e];
  part[t] = s1;
  __syncthreads();
  if (t == 0) {
    int Kv = KSEL;
    unsigned cumBefore = 0;
    int bsel = 0;
    for (int q = 255; q >= 0; --q) {
      unsigned ps = part[q];
      if ((int)(cumBefore + ps) >= Kv) {
        for (int e = q * 8 + 7;; --e) {
          unsigned c2 = cumBefore + h[e];
          if ((int)c2 >= Kv) { bsel = e; break; }
          cumBefore = c2;
        }
        break;
      }
      cumBefore += ps;
    }
    b1_sh = bsel;
    k1_sh = KSEL - (int)cumBefore;
  }
  __syncthreads();
  unsigned b1x = (unsigned)b1_sh;
  for (int e = t; e < 1024; e += 256) h[e] = 0;
  __syncthreads();
  for (int e = t; e < n; e += 256) {
    unsigned u = __float_as_uint(cv[e]) & 0x7fffffffu;
    if ((u >> 20) == b1x) atomicAdd(&h[(u >> 10) & 1023], 1u);
  }
  __syncthreads();
  part[t] = h[t * 4] + h[t * 4 + 1] + h[t * 4 + 2] + h[t * 4 + 3];
  __syncthreads();
  if (t == 0) {
    int Kv = k1_sh;
    unsigned cumBefore = 0;
    int bsel = 0;
    for (int q = 255; q >= 0; --q) {
      unsigned ps = part[q];
      if ((int)(cumBefore + ps) >= Kv) {
        for (int e = q * 4 + 3;; --e) {
          unsigned c2 = cumBefore + h[e];
          if ((int)c2 >= Kv) { bsel = e; break; }
          cumBefore = c2;
        }
        break;
      }
      cumBefore += ps;
    }
    b2_sh = bsel;
    k2_sh = Kv - (int)cumBefore;
  }
  __syncthreads();
  for (int e = t; e < 1024; e += 256) h[e] = 0;
  __syncthreads();
  unsigned pre21 = (b1x << 10) | (unsigned)b2_sh;
  for (int e = t; e < n; e += 256) {
    unsigned u = __float_as_uint(cv[e]) & 0x7fffffffu;
    if ((u >> 10) == pre21) atomicAdd(&h[u & 1023], 1u);
  }
  __syncthreads();
  if (t == 0) {
    int Kv = k2_sh;
    unsigned cumBefore = 0;
    int b3 = 0;
    for (int e = 1023; e >= 0; --e) {
      unsigned c2 = cumBefore + h[e];
      if ((int)c2 >= Kv) { b3 = e; break; }
      cumBefore = c2;
    }
    tau_sh = (pre21 << 10) | (unsigned)b3;
    k3_sh = Kv - (int)cumBefore;
  }
  __syncthreads();
  unsigned tau = tau_sh;
  for (int e = t; e < n; e += 256) {
    unsigned u = __float_as_uint(cv[e]) & 0x7fffffffu;
    if (u == tau) {
      int pos = atomicAdd(&eqn, 1);
      if (pos < 1024) eqidx[pos] = cs[e];
    }
  }
  __syncthreads();
  if (t == 0) {
    int m = eqn < 1024 ? eqn : 1024;
    int k3 = k3_sh;
    int cutoff;
    if (k3 >= m) {
      cutoff = 0x7fffffff;
    } else {
      int last = -1;
      for (int r = 0; r < k3; ++r) {
        int mn = 0x7fffffff;
        for (int q = 0; q < m; ++q) {
          int v = eqidx[q];
          if (v > last && v < mn) mn = v;
        }
        last = mn;
      }
      cutoff = last;
    }
    cutoff_sh = cutoff;
  }
  __syncthreads();
  int co = cutoff_sh;
  float* Xs = Xo + (size_t)s * NPS;
  for (int e = t; e < n; e += 256) {
    int i = cs[e];
    float cf = cv[e];
    unsigned u = __float_as_uint(cf) & 0x7fffffffu;
    bool keep = (u > tau) || (u == tau && i <= co);
    Xs[i] = keep ? cf : 0.0f;
    if (keep && emit) {
      int pos = atomicAdd(&kcnt, 1);
      if (pos < 2048) { kidx[pos] = i; kval[pos] = cf; }
    }
  }
  __syncthreads();
  if (emit) {
    int kn = kcnt < KSEL ? kcnt : KSEL;
    for (int e = t; e < kn; e += 256) {
      nzidx[s * KSEL + e] = kidx[e];
      nzval[s * KSEL + e] = kval[e];
    }
  }
  unsigned* hg1 = g1 + (size_t)s * 2048;
  for (int e = t; e < 2048; e += 256) hg1[e] = 0;
  if (t == 0) candcnt[s] = 0;
}

extern "C" void kernel_launch(void* const* d_in, const int* in_sizes, int n_in,
                              void* d_out, int out_size, void* d_ws, size_t ws_size,
                              hipStream_t stream) {
  const float* Y  = (const float*)d_in[0];
  const float* X0 = (const float*)d_in[1];
  const float* Wg = (const float*)d_in[2];
  float* Xout = (float*)d_out;

  double* WDd  = (double*)d_ws;                        // NW f64
  float* Wt2f  = (float*)(WDd + NW);                   // NW f32
  float* Wcand = Wt2f + NW;                            // NWC f32
  float* HT   = Wcand + NWC;                           // NTOT f32
  float* Rbuf = HT + NTOT;                             // RTOT f32
  double* Rd  = (double*)(Rbuf + RTOT);                // RTOT f64
  unsigned* g1 = (unsigned*)(Rd + RTOT);               // 32*2048
  int* candcnt = (int*)(g1 + 32 * 2048);               // 32
  int* cand = candcnt + 32;                            // 32*CANDCAP
  float* candval = (float*)(cand + 32 * CANDCAP);      // 32*CANDCAP
  int* nzidx = (int*)(candval + 32 * CANDCAP);         // 32*KSEL
  float* nzval = (float*)(nzidx + 32 * KSEL);          // 32*KSEL

  prep_k<<<dim3((RTOT + 255) / 256), dim3(256), 0, stream>>>(
      Wg, WDd, Wt2f, Wcand, Y, Rd, g1);

  for (int it = 0; it < 3; ++it) {
    if (it == 0) {
      convD_k<<<dim3(2048), dim3(256), 0, stream>>>(X0, WDd, Rd);
      convDt_k<double><<<dim3(4096), dim3(256), 0, stream>>>(Rd, Wt2f, X0, HT, g1);
      histwrite_k<double><<<dim3(BATCH * 32), dim3(256), 0, stream>>>(
          HT, g1, Rd, Wcand, X0, cand, candcnt, candval, Xout);
    } else {
      convD_sparse_k<<<dim3(BATCH * CCH * 8), dim3(256), 0, stream>>>(
          Wg, nzidx, nzval, Y, Rbuf);
      convDt_k<float><<<dim3(4096), dim3(256), 0, stream>>>(Rbuf, Wt2f,
          (const float*)Xout, HT, g1);
      histwrite_k<float><<<dim3(BATCH * 32), dim3(256), 0, stream>>>(
          HT, g1, Rbuf, Wcand, (const float*)Xout, cand, candcnt, candval, Xout);
    }
    int emit = (it < 2) ? 1 : 0;
    pass3_k<<<dim3(BATCH), dim3(256), 0, stream>>>(
        cand, candcnt, candval, g1, Xout, nzidx, nzval, emit);
  }
}

// Round 19
// 916.924 us; speedup vs baseline: 1.4475x; 1.0360x over previous
//
#include <hip/hip_runtime.h>

#define BATCH 32
#define ATOMS 128
#define CCH 3
#define XH 57
#define XW 57
#define OHH 64
#define OWW 64
#define KSEL 2000
#define PIX (XH*XW)            // 3249
#define NPS (ATOMS*PIX)        // 415872
#define NTOT (BATCH*NPS)       // 13307904
#define RPS (CCH*OHH*OWW)      // 12288
#define RTOT (BATCH*RPS)       // 393216
#define CANDCAP 32768
#define NW 24576
#define NWC 32768              // Wcand padded: 128 atoms x 256
#define WCAP 1536              // per-wave candidate cap (4 waves -> 6144/block)
#define ZWORDS (32*2048 + 32)  // g1 + candcnt

// ---------------------------------------------------------------------------
// Prep (once): WDf f32 [a][kh][c][kw] (convD), Wt2f f32 (convDt), Wcand f32
// (exact dot, 192 contiguous per atom), Rd = -Y (f64), zero g1/candcnt.
// ---------------------------------------------------------------------------
__global__ __launch_bounds__(256) void prep_k(const float* __restrict__ Wg,
    float* __restrict__ WDf, float* __restrict__ Wt2f,
    float* __restrict__ Wcand, const float* __restrict__ Y,
    double* __restrict__ Rd, unsigned* __restrict__ zbuf) {
  int e = blockIdx.x * 256 + threadIdx.x;
  if (e < NW) {
    {
      int kw = e & 7; int t = e >> 3; int c = t % 3; t /= 3; int kh = t & 7; int a = t >> 3;
      WDf[e] = Wg[(a*3 + c)*64 + kh*8 + kw];
    }
    {
      int a = e & 127; int t = e >> 7; int j = t & 7; int i = (t >> 3) & 7; int c = t >> 6;
      Wt2f[e] = Wg[(a*3 + c)*64 + j*8 + i];   // [c][i][j][a], exact f32
    }
  }
  if (e < NWC) {
    int a = e >> 8, r = e & 255;
    float v = 0.0f;
    if (r < 192) {
      int c = r >> 6, ii = (r >> 3) & 7, jj = r & 7;
      v = Wg[(a*3 + c)*64 + jj*8 + ii];       // Wcand[a][(c*8+ii)*8+jj]=W[a,c,jj,ii]
    }
    Wcand[e] = v;
  }
  if (e < RTOT) Rd[e] = -(double)Y[e];
  if (e < ZWORDS) zbuf[e] = 0;
}

// ---------------------------------------------------------------------------
// DENSE R += D(X) (iteration 0 only). r8-verified structure, f32 compute:
// f32 staging (no cvt), f32 FMA (2-cyc issue), per-thread f32 accumulators,
// cast to f64 ONLY at the final atomicAdd into Rd (deterministic to 1e-16).
// Block = (b, 4-row band, atom-quarter); 4 chunks x 8 atoms staged;
// wave handles 2 atoms/chunk. grid = 2048 (XCD-swizzled).
// ---------------------------------------------------------------------------
__global__ __launch_bounds__(256) void convD_k(const float* __restrict__ X,
    const float* __restrict__ WDf, double* __restrict__ Rd) {
  __shared__ float Xs[8][11][72];             // 25344 B
  int p = blockIdx.x;
  int lg = (p & 7) * 256 + (p >> 3);          // bijective: 2048 = 8*256
  int b = lg >> 6; int rem = lg & 63;
  int band = rem >> 2, quarter = rem & 3;
  int row0 = band * 4;
  int a_base = quarter * 32;
  int tid = threadIdx.x;
  int ox = tid & 63;
  int wv = __builtin_amdgcn_readfirstlane(tid >> 6);
  const float* Xb = X + (size_t)b * NPS;

  float acc[4][3];
#pragma unroll
  for (int ty = 0; ty < 4; ++ty)
#pragma unroll
    for (int c = 0; c < 3; ++c) acc[ty][c] = 0.0f;

  for (int ch = 0; ch < 4; ++ch) {
    __syncthreads();
    for (int e = tid; e < 8 * 11 * 72; e += 256) {
      int ai = e / 792; int rem2 = e - ai * 792;
      int r = rem2 / 72; int ss = rem2 - r * 72;
      int gy = row0 - 7 + r;
      int xcol = ss - 7;
      int a = a_base + ch * 8 + ai;
      float v = 0.0f;
      if ((unsigned)xcol < (unsigned)XW && (unsigned)gy < (unsigned)XH)
        v = Xb[a * PIX + gy * XW + xcol];
      Xs[ai][r][ss] = v;
    }
    __syncthreads();
#pragma unroll
    for (int jj = 0; jj < 2; ++jj) {
      int ai = (wv << 1) + jj;
      int a  = a_base + ch * 8 + ai;
      const float* Wa = WDf + a * 192;        // [kh][c][kw], uniform s_load
#pragma unroll
      for (int r = 0; r < 11; ++r) {
        int gy = row0 - 7 + r;
        if ((unsigned)gy >= (unsigned)XH) continue;   // uniform
        float xd[8];
#pragma unroll
        for (int t = 0; t < 8; ++t) xd[t] = Xs[ai][r][ox + t];
#pragma unroll
        for (int ty = 0; ty < 4; ++ty) {
          int kh = ty + 7 - r;
          if ((unsigned)kh < 8u) {
            const float* Wk = Wa + kh * 24;
#pragma unroll
            for (int kw = 0; kw < 8; ++kw) {
              acc[ty][0] = fmaf(xd[7 - kw], Wk[kw],      acc[ty][0]);
              acc[ty][1] = fmaf(xd[7 - kw], Wk[8 + kw],  acc[ty][1]);
              acc[ty][2] = fmaf(xd[7 - kw], Wk[16 + kw], acc[ty][2]);
            }
          }
        }
      }
    }
  }
#pragma unroll
  for (int ty = 0; ty < 4; ++ty) {
    int oy = row0 + ty;
#pragma unroll
    for (int c = 0; c < 3; ++c)
      atomicAdd(&Rd[((size_t)(b * CCH + c) << 12) + (oy << 6) + ox],
                (double)acc[ty][c]);
  }
}

// ---------------------------------------------------------------------------
// SPARSE R = D(X) - Y (iterations 1,2). Verified, unchanged.
// ---------------------------------------------------------------------------
__global__ __launch_bounds__(256) void convD_sparse_k(const float* __restrict__ Wg,
    const int* __restrict__ nzidx, const float* __restrict__ nzval,
    const float* __restrict__ Y, float* __restrict__ R) {
  __shared__ double accd[512];       // [rr][ox]
  __shared__ float Wf[8192];         // [a][kh][kw] for this c
  __shared__ int   li[KSEL];
  __shared__ float lv[KSEL];
  int p = blockIdx.x;
  int lg = (p & 7) * 96 + (p >> 3);  // bijective: 768 = 8*96
  int s = lg / 24; int r = lg % 24; int c = r >> 3; int band = r & 7;
  int row0 = band * 8;
  int tid = threadIdx.x;
  for (int e = tid; e < 512; e += 256) accd[e] = 0.0;
  for (int e = tid; e < 8192; e += 256) {
    int a = e >> 6, k2 = e & 63;
    Wf[e] = Wg[(a * 3 + c) * 64 + k2];
  }
  for (int e = tid; e < KSEL; e += 256) {
    li[e] = nzidx[s * KSEL + e];
    lv[e] = nzval[s * KSEL + e];
  }
  __syncthreads();
  int slot = tid >> 3, kw = tid & 7;
  for (int e = slot; e < KSEL; e += 32) {
    int idx = li[e];
    int a = (int)((unsigned)idx / 3249u);
    int pp = idx - a * 3249;
    int y = (int)((unsigned)pp / 57u);
    int x = pp - y * 57;
    int dy = y - row0;
    if (dy < -7 || dy > 7) continue;
    double val = (double)lv[e];
    const float* wp = Wf + (a << 6) + kw;
#pragma unroll
    for (int kh = 0; kh < 8; ++kh) {
      int rr = dy + kh;
      if ((unsigned)rr < 8u)
        __hip_atomic_fetch_add(&accd[(rr << 6) + x + kw],
                               val * (double)wp[kh << 3],
                               __ATOMIC_RELAXED, __HIP_MEMORY_SCOPE_WORKGROUP);
    }
  }
  __syncthreads();
  const float* Yb = Y + (((size_t)(s * CCH + c)) << 12) + (row0 << 6);
  float* Rb = R + (((size_t)(s * CCH + c)) << 12) + (row0 << 6);
  for (int e = tid; e < 512; e += 256)
    Rb[e] = (float)(accd[e] - (double)Yb[e]);
}

// ---------------------------------------------------------------------------
// HT~ = Xprev - Dt(R) in f32 (classification only), fused L1 hist.
// r14-r18 verified, unchanged.
// ---------------------------------------------------------------------------
template <typename TR>
__global__ __launch_bounds__(256) void convDt_k(const TR* __restrict__ R,
    const float* __restrict__ Wt2f, const float* __restrict__ Xprev,
    float* __restrict__ HT, unsigned* __restrict__ g1) {
  __shared__ float Rl[3][15][72];
  __shared__ unsigned hh[1024];      // packed: 2 u16 bins per word
  int p = blockIdx.x;
  int lg = (p & 7) * 512 + (p >> 3);  // bijective: 4096 = 8*512
  int b = lg >> 7; int rem = lg & 127; int ag = rem >> 3; int by = rem & 7;
  int row0 = by * 8;
  int a0 = ag * 8;
  int tid = threadIdx.x;
  for (int e = tid; e < 1024; e += 256) hh[e] = 0;
  for (int e = tid; e < 3 * 15 * 72; e += 256) {
    int c = e / (15 * 72); int r2 = e - c * (15 * 72);
    int rr = r2 / 72; int cc = r2 - rr * 72;
    int gr = row0 + rr;
    float v = 0.0f;
    if (cc < OWW && gr < OHH)
      v = (float)R[((size_t)(b * CCH + c) << 12) + (gr << 6) + cc];
    Rl[c][rr][cc] = v;
  }
  __syncthreads();
  int x = tid & 63, yg = tid >> 6;
  int yb = yg * 2;
  float acc[8][2];
#pragma unroll
  for (int aa = 0; aa < 8; ++aa) { acc[aa][0] = 0.0f; acc[aa][1] = 0.0f; }

#pragma unroll 1
  for (int c = 0; c < 3; ++c) {
#pragma unroll 1
    for (int j = 0; j < 8; ++j) {
      float rw[9];
#pragma unroll
      for (int r = 0; r < 9; ++r) rw[r] = Rl[c][yb + r][x + j];
#pragma unroll
      for (int i = 0; i < 8; ++i) {
        const float* wp = Wt2f + ((c * 8 + i) * 8 + j) * 128 + a0;  // uniform
#pragma unroll
        for (int aa = 0; aa < 8; ++aa) {
          float w = wp[aa];
          acc[aa][0] = fmaf(rw[i + 0], w, acc[aa][0]);
          acc[aa][1] = fmaf(rw[i + 1], w, acc[aa][1]);
        }
      }
    }
  }
  if (x < XW) {
#pragma unroll
    for (int ty = 0; ty < 2; ++ty) {
      int yy = row0 + yb + ty;
      if (yy < XH) {
#pragma unroll
        for (int aa = 0; aa < 8; ++aa) {
          size_t xo = (size_t)(b * ATOMS + a0 + aa) * PIX + yy * XW + x;
          float fv = Xprev[xo] - acc[aa][ty];
          HT[xo] = fv;
          unsigned u = __float_as_uint(fv) & 0x7fffffffu;
          unsigned bin = u >> 20;
          atomicAdd(&hh[bin >> 1], 1u << ((bin & 1) << 4));
        }
      }
    }
  }
  __syncthreads();
  unsigned* gp = g1 + (size_t)b * 2048;
  for (int e = tid; e < 1024; e += 256) {
    unsigned v = hh[e];
    unsigned lo = v & 0xffffu, hi = v >> 16;
    if (lo) atomicAdd(&gp[2 * e], lo);
    if (hi) atomicAdd(&gp[2 * e + 1], hi);
  }
}

// ---------------------------------------------------------------------------
// histwrite_k (recompute fused): 2-bin safety band classify; per-wave
// candidate lists; candidate lanes skip the store; exact f64 re-eval from
// Wcand + Xp. r18 verified, unchanged.
// ---------------------------------------------------------------------------
template <typename TR>
__global__ __launch_bounds__(256) void histwrite_k(const float* __restrict__ HT,
    const unsigned* __restrict__ g1, const TR* __restrict__ R,
    const float* __restrict__ Wcand, const float* Xp,
    int* __restrict__ cand, int* __restrict__ candcnt,
    float* __restrict__ candval, float* Xo) {
  __shared__ unsigned part[256];
  __shared__ int lidx[4][WCAP];
  __shared__ int wcnt[4];
  __shared__ int lbase, b1_sh;
  int tid = threadIdx.x;
  int wv = tid >> 6;
  int s = blockIdx.x >> 5;
  int chunk = blockIdx.x & 31;
  const unsigned* hg1 = g1 + (size_t)s * 2048;
  unsigned psum = 0;
#pragma unroll
  for (int e = 0; e < 8; ++e) psum += hg1[tid * 8 + e];
  part[tid] = psum;
  if (tid < 4) wcnt[tid] = 0;
  __syncthreads();
  if (tid == 0) {
    int Kv = KSEL;
    unsigned cumBefore = 0;
    int bsel = 0;
    for (int q = 255; q >= 0; --q) {
      unsigned ps = part[q];
      if ((int)(cumBefore + ps) >= Kv) {
        for (int e = q * 8 + 7;; --e) {
          unsigned c2 = cumBefore + hg1[e];
          if ((int)c2 >= Kv) { bsel = e; break; }
          cumBefore = c2;
        }
        break;
      }
      cumBefore += ps;
    }
    b1_sh = bsel;
  }
  __syncthreads();
  unsigned blo = (unsigned)(b1_sh >= 2 ? b1_sh - 2 : 0);
  size_t sbase = (size_t)s * NPS;
  const uint4* U4 = (const uint4*)(HT + sbase);
  float4* X4 = (float4*)(Xo + sbase);
  for (int i4 = chunk * 256 + tid; i4 < NPS / 4; i4 += 32 * 256) {
    uint4 v = U4[i4];
    unsigned uu[4] = {v.x, v.y, v.z, v.w};
    int m = 0;
#pragma unroll
    for (int t = 0; t < 4; ++t) {
      unsigned u = uu[t] & 0x7fffffffu;
      if ((u >> 20) >= blo) {
        m |= 1 << t;
        int pos = atomicAdd(&wcnt[wv], 1);
        if (pos < WCAP) lidx[wv][pos] = i4 * 4 + t;
      }
    }
    if (m == 0) {
      X4[i4] = make_float4(0.0f, 0.0f, 0.0f, 0.0f);
    } else {
#pragma unroll
      for (int t = 0; t < 4; ++t)
        if (!(m & (1 << t))) Xo[sbase + i4 * 4 + t] = 0.0f;
    }
  }
  __syncthreads();
  int wn[4], woff[4];
  {
    int acc2 = 0;
#pragma unroll
    for (int q = 0; q < 4; ++q) {
      wn[q] = wcnt[q] < WCAP ? wcnt[q] : WCAP;
      woff[q] = acc2;
      acc2 += wn[q];
    }
    if (tid == 0) lbase = atomicAdd(&candcnt[s], acc2);
  }
  __syncthreads();
  const TR* Rb = R + ((size_t)(s * 3) << 12);
  int ntot = wn[0] + wn[1] + wn[2] + wn[3];
  for (int e = tid; e < ntot; e += 256) {
    int q = 0, eo = e;
    while (q < 3 && eo >= wn[q]) { eo -= wn[q]; ++q; }
    int i = lidx[q][eo];
    int g = lbase + woff[q] + eo;
    int a = (int)((unsigned)i / 3249u);
    int p = i - a * 3249;
    int y = (int)((unsigned)p / 57u);
    int x = p - y * 57;
    double xprev = (double)Xp[sbase + i];     // candidate lane: never zeroed
    const float* wa = Wcand + (a << 8);
    double acc = 0.0;
    for (int c = 0; c < 3; ++c) {
#pragma unroll
      for (int ii = 0; ii < 8; ++ii) {
        const TR* rrow = Rb + (c << 12) + ((y + ii) << 6) + x;
        const float* wrow = wa + (c * 8 + ii) * 8;
#pragma unroll
        for (int jj = 0; jj < 8; ++jj)
          acc = fma((double)rrow[jj], (double)wrow[jj], acc);
      }
    }
    float cf = (float)(xprev - acc);
    if (g < CANDCAP) {
      cand[s * CANDCAP + g] = i;
      candval[s * CANDCAP + g] = cf;
    }
  }
}

// ---------------------------------------------------------------------------
// pass3_k: exact 3-level radix select over candidate values (self-computed
// L1 hist), tie resolution by lowest index, Xout fixup, nz-list emit,
// per-sample g1/candcnt reset. r16/r18 verified, unchanged.
// ---------------------------------------------------------------------------
__global__ __launch_bounds__(256) void pass3_k(const int* __restrict__ cand,
    int* __restrict__ candcnt, const float* __restrict__ candval,
    unsigned* __restrict__ g1, float* __restrict__ Xo,
    int* __restrict__ nzidx, float* __restrict__ nzval, int emit) {
  int s = blockIdx.x;
  __shared__ unsigned h[2048];
  __shared__ unsigned part[256];
  __shared__ int eqidx[1024];
  __shared__ int kidx[2048];
  __shared__ float kval[2048];
  __shared__ int eqn, kcnt;
  __shared__ unsigned tau_sh;
  __shared__ int k3_sh, cutoff_sh, b1_sh, k1_sh, b2_sh, k2_sh;
  int t = threadIdx.x;
  int n = candcnt[s];
  if (n > CANDCAP) n = CANDCAP;
  const int* cs = cand + s * CANDCAP;
  const float* cv = candval + s * CANDCAP;
  for (int e = t; e < 2048; e += 256) h[e] = 0;
  if (t == 0) { eqn = 0; kcnt = 0; }
  __syncthreads();
  for (int e = t; e < n; e += 256) {
    unsigned u = __float_as_uint(cv[e]) & 0x7fffffffu;
    atomicAdd(&h[u >> 20], 1u);
  }
  __syncthreads();
  unsigned s1 = 0;
#pragma unroll
  for (int e = 0; e < 8; ++e) s1 += h[t * 8 + e];
  part[t] = s1;
  __syncthreads();
  if (t == 0) {
    int Kv = KSEL;
    unsigned cumBefore = 0;
    int bsel = 0;
    for (int q = 255; q >= 0; --q) {
      unsigned ps = part[q];
      if ((int)(cumBefore + ps) >= Kv) {
        for (int e = q * 8 + 7;; --e) {
          unsigned c2 = cumBefore + h[e];
          if ((int)c2 >= Kv) { bsel = e; break; }
          cumBefore = c2;
        }
        break;
      }
      cumBefore += ps;
    }
    b1_sh = bsel;
    k1_sh = KSEL - (int)cumBefore;
  }
  __syncthreads();
  unsigned b1x = (unsigned)b1_sh;
  for (int e = t; e < 1024; e += 256) h[e] = 0;
  __syncthreads();
  for (int e = t; e < n; e += 256) {
    unsigned u = __float_as_uint(cv[e]) & 0x7fffffffu;
    if ((u >> 20) == b1x) atomicAdd(&h[(u >> 10) & 1023], 1u);
  }
  __syncthreads();
  part[t] = h[t * 4] + h[t * 4 + 1] + h[t * 4 + 2] + h[t * 4 + 3];
  __syncthreads();
  if (t == 0) {
    int Kv = k1_sh;
    unsigned cumBefore = 0;
    int bsel = 0;
    for (int q = 255; q >= 0; --q) {
      unsigned ps = part[q];
      if ((int)(cumBefore + ps) >= Kv) {
        for (int e = q * 4 + 3;; --e) {
          unsigned c2 = cumBefore + h[e];
          if ((int)c2 >= Kv) { bsel = e; break; }
          cumBefore = c2;
        }
        break;
      }
      cumBefore += ps;
    }
    b2_sh = bsel;
    k2_sh = Kv - (int)cumBefore;
  }
  __syncthreads();
  for (int e = t; e < 1024; e += 256) h[e] = 0;
  __syncthreads();
  unsigned pre21 = (b1x << 10) | (unsigned)b2_sh;
  for (int e = t; e < n; e += 256) {
    unsigned u = __float_as_uint(cv[e]) & 0x7fffffffu;
    if ((u >> 10) == pre21) atomicAdd(&h[u & 1023], 1u);
  }
  __syncthreads();
  if (t == 0) {
    int Kv = k2_sh;
    unsigned cumBefore = 0;
    int b3 = 0;
    for (int e = 1023; e >= 0; --e) {
      unsigned c2 = cumBefore + h[e];
      if ((int)c2 >= Kv) { b3 = e; break; }
      cumBefore = c2;
    }
    tau_sh = (pre21 << 10) | (unsigned)b3;
    k3_sh = Kv - (int)cumBefore;
  }
  __syncthreads();
  unsigned tau = tau_sh;
  for (int e = t; e < n; e += 256) {
    unsigned u = __float_as_uint(cv[e]) & 0x7fffffffu;
    if (u == tau) {
      int pos = atomicAdd(&eqn, 1);
      if (pos < 1024) eqidx[pos] = cs[e];
    }
  }
  __syncthreads();
  if (t == 0) {
    int m = eqn < 1024 ? eqn : 1024;
    int k3 = k3_sh;
    int cutoff;
    if (k3 >= m) {
      cutoff = 0x7fffffff;
    } else {
      int last = -1;
      for (int r = 0; r < k3; ++r) {
        int mn = 0x7fffffff;
        for (int q = 0; q < m; ++q) {
          int v = eqidx[q];
          if (v > last && v < mn) mn = v;
        }
        last = mn;
      }
      cutoff = last;
    }
    cutoff_sh = cutoff;
  }
  __syncthreads();
  int co = cutoff_sh;
  float* Xs = Xo + (size_t)s * NPS;
  for (int e = t; e < n; e += 256) {
    int i = cs[e];
    float cf = cv[e];
    unsigned u = __float_as_uint(cf) & 0x7fffffffu;
    bool keep = (u > tau) || (u == tau && i <= co);
    Xs[i] = keep ? cf : 0.0f;
    if (keep && emit) {
      int pos = atomicAdd(&kcnt, 1);
      if (pos < 2048) { kidx[pos] = i; kval[pos] = cf; }
    }
  }
  __syncthreads();
  if (emit) {
    int kn = kcnt < KSEL ? kcnt : KSEL;
    for (int e = t; e < kn; e += 256) {
      nzidx[s * KSEL + e] = kidx[e];
      nzval[s * KSEL + e] = kval[e];
    }
  }
  unsigned* hg1 = g1 + (size_t)s * 2048;
  for (int e = t; e < 2048; e += 256) hg1[e] = 0;
  if (t == 0) candcnt[s] = 0;
}

extern "C" void kernel_launch(void* const* d_in, const int* in_sizes, int n_in,
                              void* d_out, int out_size, void* d_ws, size_t ws_size,
                              hipStream_t stream) {
  const float* Y  = (const float*)d_in[0];
  const float* X0 = (const float*)d_in[1];
  const float* Wg = (const float*)d_in[2];
  float* Xout = (float*)d_out;

  float* WDf   = (float*)d_ws;                         // NW f32
  float* Wt2f  = WDf + NW;                             // NW f32
  float* Wcand = Wt2f + NW;                            // NWC f32
  float* HT   = Wcand + NWC;                           // NTOT f32
  float* Rbuf = HT + NTOT;                             // RTOT f32
  double* Rd  = (double*)(Rbuf + RTOT);                // RTOT f64
  unsigned* g1 = (unsigned*)(Rd + RTOT);               // 32*2048
  int* candcnt = (int*)(g1 + 32 * 2048);               // 32
  int* cand = candcnt + 32;                            // 32*CANDCAP
  float* candval = (float*)(cand + 32 * CANDCAP);      // 32*CANDCAP
  int* nzidx = (int*)(candval + 32 * CANDCAP);         // 32*KSEL
  float* nzval = (float*)(nzidx + 32 * KSEL);          // 32*KSEL

  prep_k<<<dim3((RTOT + 255) / 256), dim3(256), 0, stream>>>(
      Wg, WDf, Wt2f, Wcand, Y, Rd, g1);

  for (int it = 0; it < 3; ++it) {
    if (it == 0) {
      convD_k<<<dim3(2048), dim3(256), 0, stream>>>(X0, WDf, Rd);
      convDt_k<double><<<dim3(4096), dim3(256), 0, stream>>>(Rd, Wt2f, X0, HT, g1);
      histwrite_k<double><<<dim3(BATCH * 32), dim3(256), 0, stream>>>(
          HT, g1, Rd, Wcand, X0, cand, candcnt, candval, Xout);
    } else {
      convD_sparse_k<<<dim3(BATCH * CCH * 8), dim3(256), 0, stream>>>(
          Wg, nzidx, nzval, Y, Rbuf);
      convDt_k<float><<<dim3(4096), dim3(256), 0, stream>>>(Rbuf, Wt2f,
          (const float*)Xout, HT, g1);
      histwrite_k<float><<<dim3(BATCH * 32), dim3(256), 0, stream>>>(
          HT, g1, Rbuf, Wcand, (const float*)Xout, cand, candcnt, candval, Xout);
    }
    int emit = (it < 2) ? 1 : 0;
    pass3_k<<<dim3(BATCH), dim3(256), 0, stream>>>(
        cand, candcnt, candval, g1, Xout, nzidx, nzval, emit);
  }
}